// Round 2
// baseline (356.074 us; speedup 1.0000x reference)
//
#include <hip/hip_runtime.h>
#include <string.h>

// ---------------------------------------------------------------------------
// MultiHeadAttentionBlock: q=x@Wq; k=y@Wk; v=y@Wv; attn; +x; LN1; FF+ReLU+res;
// LN2.  B=8 N=1024 D=1024 H=16 DH=64.  All heavy math in bf16 MFMA.
// ---------------------------------------------------------------------------

#define Bb 8
#define Nn 1024
#define Dd 1024
#define Hh 16
#define DH 64
#define Mrows (Bb * Nn)   // 8192

typedef float f32x4 __attribute__((ext_vector_type(4)));
typedef __bf16 bf16x8 __attribute__((ext_vector_type(8)));
typedef unsigned int u32x4 __attribute__((ext_vector_type(4)));

#define MFMA16(acc, a, b) \
  acc = __builtin_amdgcn_mfma_f32_16x16x32_bf16((a), (b), (acc), 0, 0, 0)

__device__ __forceinline__ bf16x8 ld_frag(const unsigned short* p) {
  u32x4 v = *(const u32x4*)p;           // 16B aligned LDS read
  return __builtin_bit_cast(bf16x8, v);
}

__device__ __forceinline__ unsigned short f2bf(float f) {
  unsigned int u = __builtin_bit_cast(unsigned int, f);
  u = u + 0x7FFFu + ((u >> 16) & 1u);   // round-to-nearest-even
  return (unsigned short)(u >> 16);
}
__device__ __forceinline__ float bf2f(unsigned short s) {
  unsigned int u = ((unsigned int)s) << 16;
  return __builtin_bit_cast(float, u);
}

// ---------------------------------------------------------------------------
// f32 -> bf16 cast, vectorized (float4 in, ushort4 out)
// ---------------------------------------------------------------------------
__global__ __launch_bounds__(256) void cvt_f32_bf16(
    const float* __restrict__ in, unsigned short* __restrict__ out, int n4) {
  int i = blockIdx.x * blockDim.x + threadIdx.x;
  int stride = gridDim.x * blockDim.x;
  for (; i < n4; i += stride) {
    float4 v = ((const float4*)in)[i];
    ushort4 o;
    o.x = f2bf(v.x); o.y = f2bf(v.y); o.z = f2bf(v.z); o.w = f2bf(v.w);
    ((ushort4*)out)[i] = o;
  }
}

// ---------------------------------------------------------------------------
// W [K,N] f32 row-major  ->  Wt [N,K] bf16 row-major   (Wt[n][k] = W[k][n])
// block (32,8), grid (32,32)
// ---------------------------------------------------------------------------
__global__ __launch_bounds__(256) void transpose_cvt(
    const float* __restrict__ W, unsigned short* __restrict__ Wt) {
  __shared__ float tile[32][33];
  int tx = threadIdx.x, ty = threadIdx.y;
  int n0 = blockIdx.x * 32, k0 = blockIdx.y * 32;
#pragma unroll
  for (int i = ty; i < 32; i += 8)
    tile[i][tx] = W[(size_t)(k0 + i) * Dd + n0 + tx];
  __syncthreads();
#pragma unroll
  for (int i = ty; i < 32; i += 8)
    Wt[(size_t)(n0 + i) * Dd + k0 + tx] = f2bf(tile[tx][i]);
}

// ---------------------------------------------------------------------------
// GEMM  C[M,N] = A[M,K] @ Bt[N,K]^T + bias
//   EPI==0 : C -> bf16 output Cb
//   EPI==1 : Cf = bf2f(Tres) + relu(acc + bias)   (f32 output, FF fused)
// 128x128 tile, BK=32, 256 threads (4 waves, 2x2 of 64x64).
// ---------------------------------------------------------------------------
template <int EPI>
__global__ __launch_bounds__(256) void gemm_bt(
    const unsigned short* __restrict__ A, const unsigned short* __restrict__ Bt,
    const float* __restrict__ bias, unsigned short* __restrict__ Cb,
    const unsigned short* __restrict__ Tres, float* __restrict__ Cf,
    int M, int N, int K) {
  __shared__ __attribute__((aligned(16))) unsigned short As[128][40];
  __shared__ __attribute__((aligned(16))) unsigned short Bs[128][40];
  const int m0 = blockIdx.y * 128, n0 = blockIdx.x * 128;
  const int t = threadIdx.x;
  const int w = t >> 6, l = t & 63;
  const int wm = (w >> 1) * 64, wn = (w & 1) * 64;
  const int lr = l & 15, lk = (l >> 4) * 8;

  f32x4 acc[4][4] = {};

  for (int k0 = 0; k0 < K; k0 += 32) {
    __syncthreads();  // protect LDS overwrite from previous iter's readers
#pragma unroll
    for (int cc = 0; cc < 2; ++cc) {
      int ch = t + cc * 256;           // 512 chunks of 16B per tile
      int row = ch >> 2, seg = (ch & 3) * 8;
      uint4 va = *(const uint4*)(A + (size_t)(m0 + row) * K + k0 + seg);
      *(uint4*)(&As[row][seg]) = va;
      uint4 vb = *(const uint4*)(Bt + (size_t)(n0 + row) * K + k0 + seg);
      *(uint4*)(&Bs[row][seg]) = vb;
    }
    __syncthreads();

    bf16x8 af[4], bfr[4];
#pragma unroll
    for (int i = 0; i < 4; ++i) af[i] = ld_frag(&As[wm + i * 16 + lr][lk]);
#pragma unroll
    for (int j = 0; j < 4; ++j) bfr[j] = ld_frag(&Bs[wn + j * 16 + lr][lk]);
#pragma unroll
    for (int i = 0; i < 4; ++i)
#pragma unroll
      for (int j = 0; j < 4; ++j) MFMA16(acc[i][j], af[i], bfr[j]);
  }

  const int lg = l >> 4;
#pragma unroll
  for (int i = 0; i < 4; ++i)
#pragma unroll
    for (int j = 0; j < 4; ++j) {
      int col = n0 + wn + j * 16 + lr;
      float bcol = bias[col];
#pragma unroll
      for (int r = 0; r < 4; ++r) {
        int row = m0 + wm + i * 16 + lg * 4 + r;
        float v = acc[i][j][r] + bcol;
        size_t idx = (size_t)row * N + col;
        if (EPI == 0) {
          Cb[idx] = f2bf(v);
        } else {
          Cf[idx] = bf2f(Tres[idx]) + fmaxf(v, 0.f);
        }
      }
    }
}

// ---------------------------------------------------------------------------
// Flash attention: 1 block (4 waves) per (b, h, 64 q-rows). kv tiles of 64.
// Q/K/V are bf16 [8192,1024] (col = h*64+dh). O is f32 [8192,1024].
// scale = 1/sqrt(D) = 1/32 (reference scales by sqrt(embed_dim)!).
// ---------------------------------------------------------------------------
__global__ __launch_bounds__(256) void attn_fwd(
    const unsigned short* __restrict__ Qg, const unsigned short* __restrict__ Kg,
    const unsigned short* __restrict__ Vg, float* __restrict__ O) {
  __shared__ __attribute__((aligned(16))) unsigned short Qs[64][72];
  __shared__ __attribute__((aligned(16))) unsigned short Ks[64][72];
  __shared__ __attribute__((aligned(16))) unsigned short Vts[64][72];  // [dh][kv]
  __shared__ __attribute__((aligned(16))) unsigned short Ps[64][72];

  const int q0 = blockIdx.x * 64;
  const int b = blockIdx.y >> 4, h = blockIdx.y & 15;
  const int t = threadIdx.x, w = t >> 6, l = t & 63;
  const int lr = l & 15, lk8 = (l >> 4) * 8;

  const size_t baseQ = ((size_t)b * Nn + q0) * Dd + h * DH;
#pragma unroll
  for (int cc = 0; cc < 2; ++cc) {
    int ch = t + cc * 256;             // 64 rows x 8 chunks
    int row = ch >> 3, seg = (ch & 7) * 8;
    uint4 v = *(const uint4*)(Qg + baseQ + (size_t)row * Dd + seg);
    *(uint4*)(&Qs[row][seg]) = v;
  }
  __syncthreads();

  bf16x8 aq0 = ld_frag(&Qs[w * 16 + lr][lk8]);
  bf16x8 aq1 = ld_frag(&Qs[w * 16 + lr][32 + lk8]);

  f32x4 oacc[4] = {};
  float m_r[4], l_r[4];
#pragma unroll
  for (int r = 0; r < 4; ++r) { m_r[r] = -1e30f; l_r[r] = 0.f; }

  for (int kv = 0; kv < Nn / 64; ++kv) {
    __syncthreads();  // previous iter's K/V/P readers done
    const size_t baseK = ((size_t)b * Nn + kv * 64) * Dd + h * DH;
#pragma unroll
    for (int cc = 0; cc < 2; ++cc) {
      int ch = t + cc * 256;
      int row = ch >> 3, seg = (ch & 7) * 8;
      size_t g = baseK + (size_t)row * Dd + seg;
      uint4 kk = *(const uint4*)(Kg + g);
      *(uint4*)(&Ks[row][seg]) = kk;
      uint4 vv = *(const uint4*)(Vg + g);
      union { uint4 u; unsigned short s[8]; } cv; cv.u = vv;
#pragma unroll
      for (int e = 0; e < 8; ++e) Vts[seg + e][row] = cv.s[e];  // transpose
    }
    __syncthreads();

    // S = Q @ K^T  (per wave: 16 q-rows x 64 kv)
    f32x4 sacc[4];
#pragma unroll
    for (int j = 0; j < 4; ++j) {
      bf16x8 b0 = ld_frag(&Ks[j * 16 + lr][lk8]);
      bf16x8 b1 = ld_frag(&Ks[j * 16 + lr][32 + lk8]);
      f32x4 z = {0.f, 0.f, 0.f, 0.f};
      MFMA16(z, aq0, b0);
      MFMA16(z, aq1, b1);
      sacc[j] = z;
    }

    // online softmax (row = (l>>4)*4 + r within the wave's 16 rows)
    float pj[4][4];
#pragma unroll
    for (int r = 0; r < 4; ++r) {
      float mx = -1e30f;
#pragma unroll
      for (int j = 0; j < 4; ++j) {
        float s = sacc[j][r] * 0.03125f;
        pj[j][r] = s;
        mx = fmaxf(mx, s);
      }
#pragma unroll
      for (int o = 1; o < 16; o <<= 1) mx = fmaxf(mx, __shfl_xor(mx, o, 64));
      float mnew = fmaxf(m_r[r], mx);
      float rs = 0.f;
#pragma unroll
      for (int j = 0; j < 4; ++j) {
        float e = __expf(pj[j][r] - mnew);
        pj[j][r] = e;
        rs += e;
      }
#pragma unroll
      for (int o = 1; o < 16; o <<= 1) rs += __shfl_xor(rs, o, 64);
      float f = __expf(m_r[r] - mnew);
      l_r[r] = l_r[r] * f + rs;
      m_r[r] = mnew;
#pragma unroll
      for (int j = 0; j < 4; ++j) oacc[j][r] *= f;
    }

    // P -> LDS (bf16), then O += P @ V
#pragma unroll
    for (int r = 0; r < 4; ++r) {
      int row = w * 16 + (l >> 4) * 4 + r;
#pragma unroll
      for (int j = 0; j < 4; ++j) Ps[row][j * 16 + lr] = f2bf(pj[j][r]);
    }
    __syncthreads();

    bf16x8 ap0 = ld_frag(&Ps[w * 16 + lr][lk8]);
    bf16x8 ap1 = ld_frag(&Ps[w * 16 + lr][32 + lk8]);
#pragma unroll
    for (int j = 0; j < 4; ++j) {
      bf16x8 b0 = ld_frag(&Vts[j * 16 + lr][lk8]);
      bf16x8 b1 = ld_frag(&Vts[j * 16 + lr][32 + lk8]);
      MFMA16(oacc[j], ap0, b0);
      MFMA16(oacc[j], ap1, b1);
    }
  }

  float rdiv[4];
#pragma unroll
  for (int r = 0; r < 4; ++r) rdiv[r] = 1.f / l_r[r];
#pragma unroll
  for (int j = 0; j < 4; ++j)
#pragma unroll
    for (int r = 0; r < 4; ++r) {
      int row = q0 + w * 16 + (l >> 4) * 4 + r;
      int col = h * DH + j * 16 + lr;
      O[((size_t)b * Nn + row) * Dd + col] = oacc[j][r] * rdiv[r];
    }
}

// ---------------------------------------------------------------------------
// LayerNorm over D=1024, one block (256 thr) per row.
//   MODE 0: t = LN(X + Oin) -> bf16 out_bf
//   MODE 1: out_f = LN(X)   -> f32
// ---------------------------------------------------------------------------
template <int MODE>
__global__ __launch_bounds__(256) void ln_k(
    const float* __restrict__ X, const float* __restrict__ Oin,
    const float* __restrict__ gamma, const float* __restrict__ beta,
    unsigned short* __restrict__ out_bf, float* __restrict__ out_f) {
  __shared__ float red[8];
  const int row = blockIdx.x, t = threadIdx.x;
  float4 v = ((const float4*)(X + (size_t)row * Dd))[t];
  if (MODE == 0) {
    float4 o = ((const float4*)(Oin + (size_t)row * Dd))[t];
    v.x += o.x; v.y += o.y; v.z += o.z; v.w += o.w;
  }
  float s = v.x + v.y + v.z + v.w;
#pragma unroll
  for (int o = 32; o > 0; o >>= 1) s += __shfl_xor(s, o, 64);
  if ((t & 63) == 0) red[t >> 6] = s;
  __syncthreads();
  float mean = (red[0] + red[1] + red[2] + red[3]) * (1.f / 1024.f);
  float dx = v.x - mean, dy = v.y - mean, dz = v.z - mean, dw = v.w - mean;
  float s2 = dx * dx + dy * dy + dz * dz + dw * dw;
#pragma unroll
  for (int o = 32; o > 0; o >>= 1) s2 += __shfl_xor(s2, o, 64);
  if ((t & 63) == 0) red[4 + (t >> 6)] = s2;
  __syncthreads();
  float var = (red[4] + red[5] + red[6] + red[7]) * (1.f / 1024.f);
  float rstd = rsqrtf(var + 1e-6f);
  float4 g = ((const float4*)gamma)[t];
  float4 bb = ((const float4*)beta)[t];
  float r0 = dx * rstd * g.x + bb.x;
  float r1 = dy * rstd * g.y + bb.y;
  float r2 = dz * rstd * g.z + bb.z;
  float r3 = dw * rstd * g.w + bb.w;
  if (MODE == 0) {
    ushort4 o4;
    o4.x = f2bf(r0); o4.y = f2bf(r1); o4.z = f2bf(r2); o4.w = f2bf(r3);
    ((ushort4*)(out_bf + (size_t)row * Dd))[t] = o4;
  } else {
    float4 o4 = {r0, r1, r2, r3};
    ((float4*)(out_f + (size_t)row * Dd))[t] = o4;
  }
}

// ---------------------------------------------------------------------------
extern "C" void kernel_launch(void* const* d_in, const int* in_sizes, int n_in,
                              void* d_out, int out_size, void* d_ws, size_t ws_size,
                              hipStream_t stream) {
  const float* x  = (const float*)d_in[0];
  const float* y  = (const float*)d_in[1];
  const float* Wq = (const float*)d_in[2];
  const float* bq = (const float*)d_in[3];
  const float* Wk = (const float*)d_in[4];
  const float* bk = (const float*)d_in[5];
  const float* Wv = (const float*)d_in[6];
  const float* bv = (const float*)d_in[7];
  const float* Wf = (const float*)d_in[8];
  const float* bf = (const float*)d_in[9];
  const float* g1 = (const float*)d_in[10];
  const float* b1 = (const float*)d_in[11];
  const float* g2 = (const float*)d_in[12];
  const float* b2 = (const float*)d_in[13];

  char* ws = (char*)d_ws;
  const size_t MB = 1024 * 1024;
  // workspace layout (88 MB total, with dead-buffer aliasing):
  unsigned short* xb  = (unsigned short*)(ws + 0 * MB);   // 16 MB
  unsigned short* yb  = (unsigned short*)(ws + 16 * MB);  // 16 MB
  unsigned short* WqT = (unsigned short*)(ws + 32 * MB);  // 2 MB each
  unsigned short* WkT = (unsigned short*)(ws + 34 * MB);
  unsigned short* WvT = (unsigned short*)(ws + 36 * MB);
  unsigned short* WfT = (unsigned short*)(ws + 38 * MB);
  unsigned short* Qb  = (unsigned short*)(ws + 40 * MB);  // 16 MB
  unsigned short* Kb  = (unsigned short*)(ws + 56 * MB);  // 16 MB
  unsigned short* Vb  = (unsigned short*)(ws + 72 * MB);  // 16 MB
  float* Obuf = (float*)(ws + 0 * MB);            // 32 MB, aliases xb+yb (dead)
  unsigned short* tb = (unsigned short*)(ws + 40 * MB);  // aliases Qb (dead)
  float* ubuf = (float*)(ws + 56 * MB);           // 32 MB, aliases Kb+Vb (dead)

  const int n4 = (Mrows * Dd) / 4;  // 2M float4 per tensor
  cvt_f32_bf16<<<2048, 256, 0, stream>>>(x, xb, n4);
  cvt_f32_bf16<<<2048, 256, 0, stream>>>(y, yb, n4);

  dim3 tb32(32, 8), tg(32, 32);
  transpose_cvt<<<tg, tb32, 0, stream>>>(Wq, WqT);
  transpose_cvt<<<tg, tb32, 0, stream>>>(Wk, WkT);
  transpose_cvt<<<tg, tb32, 0, stream>>>(Wv, WvT);
  transpose_cvt<<<tg, tb32, 0, stream>>>(Wf, WfT);

  dim3 gg(Dd / 128, Mrows / 128);  // (8, 64)
  gemm_bt<0><<<gg, 256, 0, stream>>>(xb, WqT, bq, Qb, nullptr, nullptr, Mrows, Dd, Dd);
  gemm_bt<0><<<gg, 256, 0, stream>>>(yb, WkT, bk, Kb, nullptr, nullptr, Mrows, Dd, Dd);
  gemm_bt<0><<<gg, 256, 0, stream>>>(yb, WvT, bv, Vb, nullptr, nullptr, Mrows, Dd, Dd);

  attn_fwd<<<dim3(Nn / 64, Bb * Hh), 256, 0, stream>>>(Qb, Kb, Vb, Obuf);

  ln_k<0><<<Mrows, 256, 0, stream>>>(x, Obuf, g1, b1, tb, nullptr);

  gemm_bt<1><<<gg, 256, 0, stream>>>(tb, WfT, bf, nullptr, tb, ubuf, Mrows, Dd, Dd);

  ln_k<1><<<Mrows, 256, 0, stream>>>(ubuf, nullptr, g2, b2, nullptr, (float*)d_out);
}

// Round 3
// 303.449 us; speedup vs baseline: 1.1734x; 1.1734x over previous
//
#include <hip/hip_runtime.h>

// ---------------------------------------------------------------------------
// MultiHeadAttentionBlock: q=x@Wq; k=y@Wk; v=y@Wv; attn; +x; LN1; FF+ReLU+res;
// LN2.  B=8 N=1024 D=1024 H=16 DH=64.  All heavy math in bf16 MFMA.
// ---------------------------------------------------------------------------

#define Bb 8
#define Nn 1024
#define Dd 1024
#define Hh 16
#define DH 64
#define Mrows (Bb * Nn)   // 8192

typedef float f32x4 __attribute__((ext_vector_type(4)));
typedef __bf16 bf16x8 __attribute__((ext_vector_type(8)));
typedef unsigned int u32x4 __attribute__((ext_vector_type(4)));

#define MFMA16(acc, a, b) \
  acc = __builtin_amdgcn_mfma_f32_16x16x32_bf16((a), (b), (acc), 0, 0, 0)

__device__ __forceinline__ bf16x8 ld_frag(const unsigned short* p) {
  u32x4 v = *(const u32x4*)p;           // 16B aligned LDS read
  return __builtin_bit_cast(bf16x8, v);
}

// async global->LDS, 16B per lane. lds dest must be wave-uniform base
// (HW adds lane*16); global src is per-lane.
__device__ __forceinline__ void gload16(const void* g, void* l) {
  __builtin_amdgcn_global_load_lds(
      (const __attribute__((address_space(1))) unsigned int*)g,
      (__attribute__((address_space(3))) unsigned int*)l, 16, 0, 0);
}

__device__ __forceinline__ unsigned short f2bf(float f) {
  unsigned int u = __builtin_bit_cast(unsigned int, f);
  u = u + 0x7FFFu + ((u >> 16) & 1u);   // round-to-nearest-even
  return (unsigned short)(u >> 16);
}
__device__ __forceinline__ float bf2f(unsigned short s) {
  unsigned int u = ((unsigned int)s) << 16;
  return __builtin_bit_cast(float, u);
}

// ---------------------------------------------------------------------------
// f32 -> bf16 cast, vectorized
// ---------------------------------------------------------------------------
__global__ __launch_bounds__(256) void cvt_f32_bf16(
    const float* __restrict__ in, unsigned short* __restrict__ out, int n4) {
  int i = blockIdx.x * blockDim.x + threadIdx.x;
  int stride = gridDim.x * blockDim.x;
  for (; i < n4; i += stride) {
    float4 v = ((const float4*)in)[i];
    ushort4 o;
    o.x = f2bf(v.x); o.y = f2bf(v.y); o.z = f2bf(v.z); o.w = f2bf(v.w);
    ((ushort4*)out)[i] = o;
  }
}

// ---------------------------------------------------------------------------
// W [K,N] f32 row-major  ->  Wt [N,K] bf16 row-major
// ---------------------------------------------------------------------------
__global__ __launch_bounds__(256) void transpose_cvt(
    const float* __restrict__ W, unsigned short* __restrict__ Wt) {
  __shared__ float tile[32][33];
  int tx = threadIdx.x, ty = threadIdx.y;
  int n0 = blockIdx.x * 32, k0 = blockIdx.y * 32;
#pragma unroll
  for (int i = ty; i < 32; i += 8)
    tile[i][tx] = W[(size_t)(k0 + i) * Dd + n0 + tx];
  __syncthreads();
#pragma unroll
  for (int i = ty; i < 32; i += 8)
    Wt[(size_t)(n0 + i) * Dd + k0 + tx] = f2bf(tile[tx][i]);
}

// ---------------------------------------------------------------------------
// GEMM  C[M,N] = A[M,K] @ Bt[N,K]^T + bias     (m97 structure:
// global_load_lds width=16 into linear LDS [128][32], 2 barriers/K-step)
//   EPI==0 : C -> bf16 output Cb
//   EPI==1 : Cf = bf2f(Tres) + relu(acc + bias)   (f32 output, FF fused)
//   EPI==2 : write C^T (bf16) into VtOut laid out [B][D][N]
// ---------------------------------------------------------------------------
template <int EPI>
__global__ __launch_bounds__(256) void gemm_bt(
    const unsigned short* __restrict__ A, const unsigned short* __restrict__ Bt,
    const float* __restrict__ bias, unsigned short* __restrict__ Cb,
    const unsigned short* __restrict__ Tres, float* __restrict__ Cf,
    unsigned short* __restrict__ VtOut, int M, int N, int K) {
  __shared__ __attribute__((aligned(16))) unsigned short As[128 * 32];
  __shared__ __attribute__((aligned(16))) unsigned short Bs[128 * 32];
  const int m0 = blockIdx.y * 128, n0 = blockIdx.x * 128;
  const int t = threadIdx.x, w = t >> 6, l = t & 63;
  const int wm = (w >> 1) * 64, wn = (w & 1) * 64;
  const int lr = l & 15, lk = (l >> 4) * 8;
  // staging: chunk c = t (+256); row = c>>2, seg = (c&3)*8; lds byte = c*16
  const int rA = t >> 2, sA = (t & 3) * 8;
  char* AsB = (char*)As;
  char* BsB = (char*)Bs;
  const int wb = (w * 64) * 16;     // wave-uniform LDS byte base

  f32x4 acc[4][4] = {};

  for (int k0 = 0; k0 < K; k0 += 32) {
    __syncthreads();                // prior readers done
    gload16(A + (size_t)(m0 + rA) * K + k0 + sA, AsB + wb);
    gload16(A + (size_t)(m0 + 64 + rA) * K + k0 + sA, AsB + wb + 4096);
    gload16(Bt + (size_t)(n0 + rA) * K + k0 + sA, BsB + wb);
    gload16(Bt + (size_t)(n0 + 64 + rA) * K + k0 + sA, BsB + wb + 4096);
    __syncthreads();                // compiler drains vmcnt before barrier

    bf16x8 af[4], bfr[4];
#pragma unroll
    for (int i = 0; i < 4; ++i) af[i] = ld_frag(&As[(wm + i * 16 + lr) * 32 + lk]);
#pragma unroll
    for (int j = 0; j < 4; ++j) bfr[j] = ld_frag(&Bs[(wn + j * 16 + lr) * 32 + lk]);
#pragma unroll
    for (int i = 0; i < 4; ++i)
#pragma unroll
      for (int j = 0; j < 4; ++j) MFMA16(acc[i][j], af[i], bfr[j]);
  }

  const int lg = l >> 4;
#pragma unroll
  for (int i = 0; i < 4; ++i)
#pragma unroll
    for (int j = 0; j < 4; ++j) {
      int col = n0 + wn + j * 16 + lr;
      float bcol = bias[col];
      if (EPI == 2) {
        int brow = m0 + wm + i * 16 + lg * 4;   // global row of r=0
        int bi = brow >> 10, nloc = brow & 1023;
        ushort4 o4;
        o4.x = f2bf(acc[i][j][0] + bcol);
        o4.y = f2bf(acc[i][j][1] + bcol);
        o4.z = f2bf(acc[i][j][2] + bcol);
        o4.w = f2bf(acc[i][j][3] + bcol);
        *(ushort4*)(VtOut + ((size_t)bi * Dd + col) * Nn + nloc) = o4;
      } else {
#pragma unroll
        for (int r = 0; r < 4; ++r) {
          int row = m0 + wm + i * 16 + lg * 4 + r;
          float v = acc[i][j][r] + bcol;
          size_t idx = (size_t)row * N + col;
          if (EPI == 0) {
            Cb[idx] = f2bf(v);
          } else {
            Cf[idx] = bf2f(Tres[idx]) + fmaxf(v, 0.f);
          }
        }
      }
    }
}

// ---------------------------------------------------------------------------
// Flash attention: 1 block (4 waves) per (b, h, 64 q-rows). kv tiles of 64.
// Q/K bf16 [8192,1024]; Vt bf16 [B][D][N] (pre-transposed). O f32 [8192,1024].
// scale = 1/sqrt(D) = 1/32 (reference scales by sqrt(embed_dim)).
// ---------------------------------------------------------------------------
__global__ __launch_bounds__(256) void attn_fwd(
    const unsigned short* __restrict__ Qg, const unsigned short* __restrict__ Kg,
    const unsigned short* __restrict__ Vt, float* __restrict__ O) {
  __shared__ __attribute__((aligned(16))) unsigned short Qs[64][72];
  __shared__ __attribute__((aligned(16))) unsigned short Ks[64][72];
  __shared__ __attribute__((aligned(16))) unsigned short Vts[64][72];  // [dh][kv]
  __shared__ __attribute__((aligned(16))) unsigned short Ps[64][72];

  const int q0 = blockIdx.x * 64;
  const int b = blockIdx.y >> 4, h = blockIdx.y & 15;
  const int t = threadIdx.x, w = t >> 6, l = t & 63;
  const int lr = l & 15, lk8 = (l >> 4) * 8;
  const int rs0 = t >> 3, seg0 = (t & 7) * 8;   // staging chunk c=t; c+256 -> row+32

  // ---- Q stage (once) ----
  const size_t baseQ = ((size_t)b * Nn + q0) * Dd + h * DH;
  *(uint4*)(&Qs[rs0][seg0])      = *(const uint4*)(Qg + baseQ + (size_t)rs0 * Dd + seg0);
  *(uint4*)(&Qs[rs0 + 32][seg0]) = *(const uint4*)(Qg + baseQ + (size_t)(rs0 + 32) * Dd + seg0);
  __syncthreads();
  bf16x8 aq0 = ld_frag(&Qs[w * 16 + lr][lk8]);
  bf16x8 aq1 = ld_frag(&Qs[w * 16 + lr][32 + lk8]);

  const size_t baseK = (size_t)b * Nn * Dd + h * DH;      // + kvrow*Dd + seg
  const size_t baseV = ((size_t)b * Dd + h * DH) * Nn;    // + dh*Nn + kvcol

  // ---- prefetch tile 0 into regs (T14 split: issue early, ds_write late) ----
  uint4 kA = *(const uint4*)(Kg + baseK + (size_t)rs0 * Dd + seg0);
  uint4 kB = *(const uint4*)(Kg + baseK + (size_t)(rs0 + 32) * Dd + seg0);
  uint4 vA = *(const uint4*)(Vt + baseV + (size_t)rs0 * Nn + seg0);
  uint4 vB = *(const uint4*)(Vt + baseV + (size_t)(rs0 + 32) * Nn + seg0);

  f32x4 oacc[4] = {};
  float m_r[4], l_r[4];
#pragma unroll
  for (int r = 0; r < 4; ++r) { m_r[r] = -1e30f; l_r[r] = 0.f; }

  for (int kv = 0; kv < Nn / 64; ++kv) {
    __syncthreads();  // all waves done reading Ks/Vts of previous iter
    *(uint4*)(&Ks[rs0][seg0]) = kA;
    *(uint4*)(&Ks[rs0 + 32][seg0]) = kB;
    *(uint4*)(&Vts[rs0][seg0]) = vA;
    *(uint4*)(&Vts[rs0 + 32][seg0]) = vB;
    __syncthreads();  // staged tile visible

    if (kv + 1 < Nn / 64) {  // issue next tile's loads; they fly across compute
      int kvo = (kv + 1) * 64;
      kA = *(const uint4*)(Kg + baseK + (size_t)(kvo + rs0) * Dd + seg0);
      kB = *(const uint4*)(Kg + baseK + (size_t)(kvo + rs0 + 32) * Dd + seg0);
      vA = *(const uint4*)(Vt + baseV + (size_t)rs0 * Nn + kvo + seg0);
      vB = *(const uint4*)(Vt + baseV + (size_t)(rs0 + 32) * Nn + kvo + seg0);
    }

    // ---- S = Q @ K^T  (per wave: 16 q-rows x 64 kv) ----
    f32x4 sacc[4];
#pragma unroll
    for (int j = 0; j < 4; ++j) {
      bf16x8 b0 = ld_frag(&Ks[j * 16 + lr][lk8]);
      bf16x8 b1 = ld_frag(&Ks[j * 16 + lr][32 + lk8]);
      f32x4 z = {0.f, 0.f, 0.f, 0.f};
      MFMA16(z, aq0, b0);
      MFMA16(z, aq1, b1);
      sacc[j] = z;
    }

    // ---- online softmax ----
    float pj[4][4];
#pragma unroll
    for (int r = 0; r < 4; ++r) {
      float mx = -1e30f;
#pragma unroll
      for (int j = 0; j < 4; ++j) {
        float s = sacc[j][r] * 0.03125f;
        pj[j][r] = s;
        mx = fmaxf(mx, s);
      }
#pragma unroll
      for (int o = 1; o < 16; o <<= 1) mx = fmaxf(mx, __shfl_xor(mx, o, 64));
      float mnew = fmaxf(m_r[r], mx);
      float rs = 0.f;
#pragma unroll
      for (int j = 0; j < 4; ++j) {
        float e = __expf(pj[j][r] - mnew);
        pj[j][r] = e;
        rs += e;
      }
#pragma unroll
      for (int o = 1; o < 16; o <<= 1) rs += __shfl_xor(rs, o, 64);
      float f = __expf(m_r[r] - mnew);
      l_r[r] = l_r[r] * f + rs;
      m_r[r] = mnew;
#pragma unroll
      for (int j = 0; j < 4; ++j) oacc[j][r] *= f;
    }

    // ---- P -> LDS (wave-private rows: no barrier, just lgkmcnt drain) ----
#pragma unroll
    for (int r = 0; r < 4; ++r) {
      int row = w * 16 + (l >> 4) * 4 + r;
#pragma unroll
      for (int j = 0; j < 4; ++j) Ps[row][j * 16 + lr] = f2bf(pj[j][r]);
    }
    asm volatile("s_waitcnt lgkmcnt(0)" ::: "memory");
    __builtin_amdgcn_sched_barrier(0);

    bf16x8 ap0 = ld_frag(&Ps[w * 16 + lr][lk8]);
    bf16x8 ap1 = ld_frag(&Ps[w * 16 + lr][32 + lk8]);
#pragma unroll
    for (int j = 0; j < 4; ++j) {
      bf16x8 bv0 = ld_frag(&Vts[j * 16 + lr][lk8]);
      bf16x8 bv1 = ld_frag(&Vts[j * 16 + lr][32 + lk8]);
      MFMA16(oacc[j], ap0, bv0);
      MFMA16(oacc[j], ap1, bv1);
    }
  }

  float rdiv[4];
#pragma unroll
  for (int r = 0; r < 4; ++r) rdiv[r] = 1.f / l_r[r];
#pragma unroll
  for (int j = 0; j < 4; ++j)
#pragma unroll
    for (int r = 0; r < 4; ++r) {
      int row = q0 + w * 16 + (l >> 4) * 4 + r;
      int col = h * DH + j * 16 + lr;
      O[((size_t)b * Nn + row) * Dd + col] = oacc[j][r] * rdiv[r];
    }
}

// ---------------------------------------------------------------------------
// LayerNorm over D=1024, one block (256 thr) per row.
//   MODE 0: t = LN(X + Oin) -> bf16 out_bf
//   MODE 1: out_f = LN(X)   -> f32
// ---------------------------------------------------------------------------
template <int MODE>
__global__ __launch_bounds__(256) void ln_k(
    const float* __restrict__ X, const float* __restrict__ Oin,
    const float* __restrict__ gamma, const float* __restrict__ beta,
    unsigned short* __restrict__ out_bf, float* __restrict__ out_f) {
  __shared__ float red[8];
  const int row = blockIdx.x, t = threadIdx.x;
  float4 v = ((const float4*)(X + (size_t)row * Dd))[t];
  if (MODE == 0) {
    float4 o = ((const float4*)(Oin + (size_t)row * Dd))[t];
    v.x += o.x; v.y += o.y; v.z += o.z; v.w += o.w;
  }
  float s = v.x + v.y + v.z + v.w;
#pragma unroll
  for (int o = 32; o > 0; o >>= 1) s += __shfl_xor(s, o, 64);
  if ((t & 63) == 0) red[t >> 6] = s;
  __syncthreads();
  float mean = (red[0] + red[1] + red[2] + red[3]) * (1.f / 1024.f);
  float dx = v.x - mean, dy = v.y - mean, dz = v.z - mean, dw = v.w - mean;
  float s2 = dx * dx + dy * dy + dz * dz + dw * dw;
#pragma unroll
  for (int o = 32; o > 0; o >>= 1) s2 += __shfl_xor(s2, o, 64);
  if ((t & 63) == 0) red[4 + (t >> 6)] = s2;
  __syncthreads();
  float var = (red[4] + red[5] + red[6] + red[7]) * (1.f / 1024.f);
  float rstd = rsqrtf(var + 1e-6f);
  float4 g = ((const float4*)gamma)[t];
  float4 bb = ((const float4*)beta)[t];
  float r0 = dx * rstd * g.x + bb.x;
  float r1 = dy * rstd * g.y + bb.y;
  float r2 = dz * rstd * g.z + bb.z;
  float r3 = dw * rstd * g.w + bb.w;
  if (MODE == 0) {
    ushort4 o4;
    o4.x = f2bf(r0); o4.y = f2bf(r1); o4.z = f2bf(r2); o4.w = f2bf(r3);
    ((ushort4*)(out_bf + (size_t)row * Dd))[t] = o4;
  } else {
    float4 o4 = {r0, r1, r2, r3};
    ((float4*)(out_f + (size_t)row * Dd))[t] = o4;
  }
}

// ---------------------------------------------------------------------------
extern "C" void kernel_launch(void* const* d_in, const int* in_sizes, int n_in,
                              void* d_out, int out_size, void* d_ws, size_t ws_size,
                              hipStream_t stream) {
  const float* x  = (const float*)d_in[0];
  const float* y  = (const float*)d_in[1];
  const float* Wq = (const float*)d_in[2];
  const float* bq = (const float*)d_in[3];
  const float* Wk = (const float*)d_in[4];
  const float* bk = (const float*)d_in[5];
  const float* Wv = (const float*)d_in[6];
  const float* bv = (const float*)d_in[7];
  const float* Wf = (const float*)d_in[8];
  const float* bf = (const float*)d_in[9];
  const float* g1 = (const float*)d_in[10];
  const float* b1 = (const float*)d_in[11];
  const float* g2 = (const float*)d_in[12];
  const float* b2 = (const float*)d_in[13];

  char* ws = (char*)d_ws;
  const size_t MB = 1024 * 1024;
  // workspace layout (88 MB total, with dead-buffer aliasing):
  unsigned short* xb  = (unsigned short*)(ws + 0 * MB);   // 16 MB
  unsigned short* yb  = (unsigned short*)(ws + 16 * MB);  // 16 MB
  unsigned short* WqT = (unsigned short*)(ws + 32 * MB);  // 2 MB each
  unsigned short* WkT = (unsigned short*)(ws + 34 * MB);
  unsigned short* WvT = (unsigned short*)(ws + 36 * MB);
  unsigned short* WfT = (unsigned short*)(ws + 38 * MB);
  unsigned short* Qb  = (unsigned short*)(ws + 40 * MB);  // 16 MB
  unsigned short* Kb  = (unsigned short*)(ws + 56 * MB);  // 16 MB
  unsigned short* Vtb = (unsigned short*)(ws + 72 * MB);  // 16 MB ([B][D][N])
  float* Obuf = (float*)(ws + 0 * MB);            // 32 MB, aliases xb+yb (dead)
  unsigned short* tb = (unsigned short*)(ws + 40 * MB);  // aliases Qb (dead)
  float* ubuf = (float*)(ws + 56 * MB);           // 32 MB, aliases Kb+Vtb (dead)

  const int n4 = (Mrows * Dd) / 4;
  cvt_f32_bf16<<<2048, 256, 0, stream>>>(x, xb, n4);
  cvt_f32_bf16<<<2048, 256, 0, stream>>>(y, yb, n4);

  dim3 tb32(32, 8), tg(32, 32);
  transpose_cvt<<<tg, tb32, 0, stream>>>(Wq, WqT);
  transpose_cvt<<<tg, tb32, 0, stream>>>(Wk, WkT);
  transpose_cvt<<<tg, tb32, 0, stream>>>(Wv, WvT);
  transpose_cvt<<<tg, tb32, 0, stream>>>(Wf, WfT);

  dim3 gg(Dd / 128, Mrows / 128);  // (8, 64)
  gemm_bt<0><<<gg, 256, 0, stream>>>(xb, WqT, bq, Qb, nullptr, nullptr, nullptr, Mrows, Dd, Dd);
  gemm_bt<0><<<gg, 256, 0, stream>>>(yb, WkT, bk, Kb, nullptr, nullptr, nullptr, Mrows, Dd, Dd);
  gemm_bt<2><<<gg, 256, 0, stream>>>(yb, WvT, bv, nullptr, nullptr, nullptr, Vtb, Mrows, Dd, Dd);

  attn_fwd<<<dim3(Nn / 64, Bb * Hh), 256, 0, stream>>>(Qb, Kb, Vtb, Obuf);

  ln_k<0><<<Mrows, 256, 0, stream>>>(x, Obuf, g1, b1, tb, nullptr);

  gemm_bt<1><<<gg, 256, 0, stream>>>(tb, WfT, bf, nullptr, tb, ubuf, nullptr, Mrows, Dd, Dd);

  ln_k<1><<<Mrows, 256, 0, stream>>>(ubuf, nullptr, g2, b2, nullptr, (float*)d_out);
}